// Round 3
// baseline (1420.032 us; speedup 1.0000x reference)
//
#include <hip/hip_runtime.h>
#include <cstddef>
#include <cstdint>

// Problem constants (match reference setup_inputs()).
#define N_NODES 100000
#define N_EDGES 640000
#define EMBD    128
#define NBATCH  16384

// Binning for the sorted scatter: 32 dst-nodes per bin.
#define BIN_NODES 32
#define NBINS     (N_NODES / BIN_NODES)   // 3125 exactly (100000 = 3125*32)

// ---------------------------------------------------------------------------
// FALLBACK scatter (round-2 path, used only if ws_size is too small):
// A[r][dst] += ew[e] * x[src], one wave per edge, global fp32 atomics.
// ---------------------------------------------------------------------------
__global__ __launch_bounds__(256) void scatter_kernel(
    const float* __restrict__ x, const int* __restrict__ ei,
    const int* __restrict__ et, const float* __restrict__ ew,
    float* __restrict__ A, int E, int N)
{
    const int lane = threadIdx.x & 63;
    const int wid  = blockIdx.x * (blockDim.x >> 6) + (threadIdx.x >> 6);
    const int nw   = gridDim.x * (blockDim.x >> 6);
    for (int e = wid; e < E; e += nw) {
        const int   src = ei[e];
        const int   dst = ei[E + e];
        const int   r   = et[e];
        const float w   = ew[e];
        const float* xr = x + (size_t)src * EMBD;
        const float v0 = xr[lane]      * w;
        const float v1 = xr[lane + 64] * w;
        float* ar = A + ((size_t)r * N + dst) * EMBD;
        atomicAdd(ar + lane,      v0);
        atomicAdd(ar + lane + 64, v1);
    }
}

// ---------------------------------------------------------------------------
// Binned scatter, phase 1: histogram of edges per dst-bin.
// ---------------------------------------------------------------------------
__global__ __launch_bounds__(256) void hist_kernel(
    const int* __restrict__ ei, int* __restrict__ hist, int E)
{
    const int e = blockIdx.x * 256 + threadIdx.x;
    if (e < E) atomicAdd(&hist[ei[E + e] >> 5], 1);
}

// ---------------------------------------------------------------------------
// Phase 2: exclusive prefix scan of 3125 bin counts (single 1024-thread
// block, 4 values/thread, Hillis-Steele on per-thread partials in LDS).
// Writes bin_start[0..NBINS] and a mutable cursor copy for bucketing.
// ---------------------------------------------------------------------------
__global__ __launch_bounds__(1024) void scan_kernel(
    const int* __restrict__ hist, int* __restrict__ bin_start,
    int* __restrict__ cursor)
{
    __shared__ int part[1024];
    const int t = threadIdx.x;
    int v[4];
    int s = 0;
#pragma unroll
    for (int i = 0; i < 4; ++i) {
        const int idx = t * 4 + i;
        v[i] = (idx < NBINS) ? hist[idx] : 0;
        s += v[i];
    }
    part[t] = s;
    __syncthreads();
    for (int off = 1; off < 1024; off <<= 1) {
        const int add = (t >= off) ? part[t - off] : 0;
        __syncthreads();
        part[t] += add;
        __syncthreads();
    }
    int run = (t == 0) ? 0 : part[t - 1];
#pragma unroll
    for (int i = 0; i < 4; ++i) {
        const int idx = t * 4 + i;
        if (idx < NBINS) { bin_start[idx] = run; cursor[idx] = run; run += v[i]; }
    }
    if (t == 0) bin_start[NBINS] = part[1023];
}

// ---------------------------------------------------------------------------
// Phase 3: bucket edges into dst-sorted order. Record packs
// src (17b) | dst_local (5b @17) | rel (1b @22) into .x, weight bits in .y.
// ---------------------------------------------------------------------------
__global__ __launch_bounds__(256) void bucket_kernel(
    const int* __restrict__ ei, const int* __restrict__ et,
    const float* __restrict__ ew, int* __restrict__ cursor,
    int2* __restrict__ srec, int E)
{
    const int e = blockIdx.x * 256 + threadIdx.x;
    if (e >= E) return;
    const int src = ei[e];
    const int dst = ei[E + e];
    const int r   = et[e];
    const int bin = dst >> 5;
    const int dl  = dst & 31;
    const int pos = atomicAdd(&cursor[bin], 1);
    srec[pos] = make_int2(src | (dl << 17) | (r << 22), __float_as_int(ew[e]));
}

// ---------------------------------------------------------------------------
// Phase 4: per-bin accumulation. One block per bin; 32 KB LDS tile
// [2 rel][32 nodes][128 dims]; LDS fp32 atomics (2-way bank alias = free);
// coalesced tile writeback. Every A row is written => no memset needed.
// ---------------------------------------------------------------------------
__global__ __launch_bounds__(256) void accum_kernel(
    const float* __restrict__ x, const int2* __restrict__ srec,
    const int* __restrict__ bin_start, float* __restrict__ A, int N)
{
    __shared__ float buf[2 * BIN_NODES * EMBD];   // 32 KB
    const int t = threadIdx.x;

    float4* b4 = (float4*)buf;
#pragma unroll
    for (int i = 0; i < 8; ++i) b4[t + 256 * i] = make_float4(0.f, 0.f, 0.f, 0.f);
    __syncthreads();

    const int bin  = blockIdx.x;
    const int s    = bin_start[bin];
    const int end  = bin_start[bin + 1];
    const int wave = t >> 6;
    const int lane = t & 63;

    int e = s + wave;
    // 2x manual unroll for ILP (two gathers in flight per wave).
    for (; e + 4 < end; e += 8) {
        const int2 ra = srec[e];
        const int2 rb = srec[e + 4];
        const float* xa = x + (size_t)(ra.x & 0x1FFFF) * EMBD;
        const float* xb = x + (size_t)(rb.x & 0x1FFFF) * EMBD;
        const float wa = __int_as_float(ra.y);
        const float wb = __int_as_float(rb.y);
        const float a0 = xa[lane] * wa, a1 = xa[lane + 64] * wa;
        const float b0 = xb[lane] * wb, b1 = xb[lane + 64] * wb;
        float* pa = buf + ((((ra.x >> 22) & 1) << 5) + ((ra.x >> 17) & 31)) * EMBD;
        float* pb = buf + ((((rb.x >> 22) & 1) << 5) + ((rb.x >> 17) & 31)) * EMBD;
        atomicAdd(pa + lane,      a0);
        atomicAdd(pa + lane + 64, a1);
        atomicAdd(pb + lane,      b0);
        atomicAdd(pb + lane + 64, b1);
    }
    if (e < end) {
        const int2 ra = srec[e];
        const float* xa = x + (size_t)(ra.x & 0x1FFFF) * EMBD;
        const float wa = __int_as_float(ra.y);
        const float a0 = xa[lane] * wa, a1 = xa[lane + 64] * wa;
        float* pa = buf + ((((ra.x >> 22) & 1) << 5) + ((ra.x >> 17) & 31)) * EMBD;
        atomicAdd(pa + lane,      a0);
        atomicAdd(pa + lane + 64, a1);
    }
    __syncthreads();

    const int base = bin * BIN_NODES;
#pragma unroll
    for (int r = 0; r < 2; ++r) {
        float4*       dst4 = (float4*)(A + ((size_t)r * N + base) * EMBD);
        const float4* src4 = (const float4*)(buf + r * BIN_NODES * EMBD);
#pragma unroll
        for (int i = 0; i < 4; ++i) dst4[t + 256 * i] = src4[t + 256 * i];
    }
}

// ---------------------------------------------------------------------------
// Fused GEMM: out[M,128] = S0@W0 + S1@W1 + S2@W2 + bias, optional ReLU+LN.
// Virtual K=384. BM=64, BN=128, BK=32. Each block reads only rows
// [m0,m0+64) of S* and writes the same rows of out after a barrier, so
// out may alias S0/S1/S2 (validated round 2).
// ---------------------------------------------------------------------------
__global__ __launch_bounds__(256) void gemm_fused(
    const float* __restrict__ S0, const float* __restrict__ S1, const float* __restrict__ S2,
    const float* __restrict__ W0, const float* __restrict__ W1, const float* __restrict__ W2,
    const float* __restrict__ bias, const float* __restrict__ lng, const float* __restrict__ lnb,
    float* __restrict__ out, int M, int do_ln)
{
    __shared__ float As[32][68];
    __shared__ float Bs[32][128];

    const int t  = threadIdx.x;
    const int tx = t & 31, ty = t >> 5;
    const int m0 = blockIdx.x * 64;

    float acc[8][4];
#pragma unroll
    for (int j = 0; j < 8; ++j)
#pragma unroll
        for (int i = 0; i < 4; ++i) acc[j][i] = 0.f;

    const float* Ss[3] = {S0, S1, S2};
    const float* Ws[3] = {W0, W1, W2};

    const int arow = t >> 3;
    const int akk  = (t & 7) * 4;
    const int brow = t >> 5;
    const int bcol = (t & 31) * 4;

    for (int kc = 0; kc < 12; ++kc) {
        const float* S = Ss[kc >> 2];
        const float* W = Ws[kc >> 2];
        const int koff = (kc & 3) * 32;

#pragma unroll
        for (int p = 0; p < 2; ++p) {
            const int row = arow + p * 32;
            const int rg  = m0 + row;
            float4 f;
            if (rg < M) f = *(const float4*)(S + (size_t)rg * EMBD + koff + akk);
            else        f = make_float4(0.f, 0.f, 0.f, 0.f);
            As[akk + 0][row] = f.x;
            As[akk + 1][row] = f.y;
            As[akk + 2][row] = f.z;
            As[akk + 3][row] = f.w;
        }
#pragma unroll
        for (int p = 0; p < 4; ++p) {
            const int row = brow + p * 8;
            float4 f = *(const float4*)(W + (size_t)(koff + row) * EMBD + bcol);
            *(float4*)&Bs[row][bcol] = f;
        }
        __syncthreads();

#pragma unroll
        for (int k = 0; k < 32; ++k) {
            const float4 a0 = *(const float4*)&As[k][ty * 8];
            const float4 a1 = *(const float4*)&As[k][ty * 8 + 4];
            const float4 b  = *(const float4*)&Bs[k][tx * 4];
            const float av[8] = {a0.x, a0.y, a0.z, a0.w, a1.x, a1.y, a1.z, a1.w};
            const float bv[4] = {b.x, b.y, b.z, b.w};
#pragma unroll
            for (int j = 0; j < 8; ++j)
#pragma unroll
                for (int i = 0; i < 4; ++i) acc[j][i] += av[j] * bv[i];
        }
        __syncthreads();
    }

    const float4 bias4 = *(const float4*)(bias + tx * 4);
    const float bb[4] = {bias4.x, bias4.y, bias4.z, bias4.w};
    float gg[4] = {0.f, 0.f, 0.f, 0.f}, bt[4] = {0.f, 0.f, 0.f, 0.f};
    if (do_ln) {
        const float4 g4 = *(const float4*)(lng + tx * 4);
        const float4 b4 = *(const float4*)(lnb + tx * 4);
        gg[0] = g4.x; gg[1] = g4.y; gg[2] = g4.z; gg[3] = g4.w;
        bt[0] = b4.x; bt[1] = b4.y; bt[2] = b4.z; bt[3] = b4.w;
    }
#pragma unroll
    for (int j = 0; j < 8; ++j) {
        const int rg = m0 + ty * 8 + j;
        float v[4];
#pragma unroll
        for (int i = 0; i < 4; ++i) v[i] = acc[j][i] + bb[i];
        if (do_ln) {
#pragma unroll
            for (int i = 0; i < 4; ++i) v[i] = fmaxf(v[i], 0.f);
            float s  = v[0] + v[1] + v[2] + v[3];
            float sq = v[0]*v[0] + v[1]*v[1] + v[2]*v[2] + v[3]*v[3];
#pragma unroll
            for (int off = 16; off > 0; off >>= 1) {
                s  += __shfl_xor(s,  off, 32);
                sq += __shfl_xor(sq, off, 32);
            }
            const float mu   = s * (1.0f / 128.0f);
            const float var  = sq * (1.0f / 128.0f) - mu * mu;
            const float rstd = rsqrtf(var + 1e-5f);
#pragma unroll
            for (int i = 0; i < 4; ++i) v[i] = (v[i] - mu) * rstd * gg[i] + bt[i];
        }
        if (rg < M) {
            *(float4*)(out + (size_t)rg * EMBD + tx * 4) = make_float4(v[0], v[1], v[2], v[3]);
        }
    }
}

// ---------------------------------------------------------------------------
// Fused head: gather u/v, l2 norms, GMF, MLP 256->128->64->32, out proj,
// sigmoid. 16 batch rows per 256-thread block, everything staged in LDS.
// ---------------------------------------------------------------------------
__global__ __launch_bounds__(256) void head_kernel(
    const float* __restrict__ x2, const int* __restrict__ ui, const int* __restrict__ vi,
    const float* __restrict__ mw0, const float* __restrict__ mb0,
    const float* __restrict__ mw1, const float* __restrict__ mb1,
    const float* __restrict__ mw2, const float* __restrict__ mb2,
    const float* __restrict__ ow, const float* __restrict__ ob,
    float* __restrict__ out, int B)
{
    __shared__ float h0[16][256];
    __shared__ float h1[16][128];
    __shared__ float h2[16][64];
    __shared__ float h3[16][32];
    __shared__ float ps_u[16][16], ps_v[16][16];
    __shared__ float inv_nunv[16];
    __shared__ float pg[16][16], ph[16][16];

    const int t   = threadIdx.x;
    const int bb0 = blockIdx.x * 16;

    for (int r = 0; r < 16; ++r) {
        const int b   = bb0 + r;
        const int idx = (t < 128) ? ui[b] : vi[b];
        const int c   = t & 127;
        h0[r][t] = x2[(size_t)idx * EMBD + c];
    }
    __syncthreads();

    {
        const int row = t >> 4, sub = t & 15;
        float su = 0.f, sv = 0.f;
#pragma unroll
        for (int k = 0; k < 8; ++k) {
            const float a = h0[row][sub + 16 * k];       su += a * a;
            const float b = h0[row][128 + sub + 16 * k]; sv += b * b;
        }
        ps_u[row][sub] = su; ps_v[row][sub] = sv;
    }
    __syncthreads();
    if (t < 16) {
        float su = 0.f, sv = 0.f;
#pragma unroll
        for (int k = 0; k < 16; ++k) { su += ps_u[t][k]; sv += ps_v[t][k]; }
        const float nu = fmaxf(sqrtf(su), 1e-12f);
        const float nv = fmaxf(sqrtf(sv), 1e-12f);
        inv_nunv[t] = 1.0f / (nu * nv);
    }
    __syncthreads();

    {
        const int c = t & 127, rr = t >> 7;
        float acc[8];
#pragma unroll
        for (int j = 0; j < 8; ++j) acc[j] = 0.f;
        for (int i = 0; i < 256; i += 4) {
            const float w0 = mw0[(i + 0) * 128 + c];
            const float w1 = mw0[(i + 1) * 128 + c];
            const float w2 = mw0[(i + 2) * 128 + c];
            const float w3 = mw0[(i + 3) * 128 + c];
#pragma unroll
            for (int j = 0; j < 8; ++j) {
                const float4 a = *(const float4*)&h0[rr * 8 + j][i];
                acc[j] += a.x * w0 + a.y * w1 + a.z * w2 + a.w * w3;
            }
        }
        const float bv = mb0[c];
#pragma unroll
        for (int j = 0; j < 8; ++j) h1[rr * 8 + j][c] = fmaxf(acc[j] + bv, 0.f);
    }
    __syncthreads();

    {
        const int c = t & 63, g = t >> 6;
        float acc[4] = {0.f, 0.f, 0.f, 0.f};
        for (int i = 0; i < 128; i += 4) {
            const float w0 = mw1[(i + 0) * 64 + c];
            const float w1 = mw1[(i + 1) * 64 + c];
            const float w2 = mw1[(i + 2) * 64 + c];
            const float w3 = mw1[(i + 3) * 64 + c];
#pragma unroll
            for (int j = 0; j < 4; ++j) {
                const float4 a = *(const float4*)&h1[g * 4 + j][i];
                acc[j] += a.x * w0 + a.y * w1 + a.z * w2 + a.w * w3;
            }
        }
        const float bv = mb1[c];
#pragma unroll
        for (int j = 0; j < 4; ++j) h2[g * 4 + j][c] = fmaxf(acc[j] + bv, 0.f);
    }
    __syncthreads();

    {
        const int c = t & 31, g = t >> 5;
        float acc[2] = {0.f, 0.f};
        for (int i = 0; i < 64; i += 4) {
            const float w0 = mw2[(i + 0) * 32 + c];
            const float w1 = mw2[(i + 1) * 32 + c];
            const float w2 = mw2[(i + 2) * 32 + c];
            const float w3 = mw2[(i + 3) * 32 + c];
#pragma unroll
            for (int j = 0; j < 2; ++j) {
                const float4 a = *(const float4*)&h2[g * 2 + j][i];
                acc[j] += a.x * w0 + a.y * w1 + a.z * w2 + a.w * w3;
            }
        }
        const float bv = mb2[c];
#pragma unroll
        for (int j = 0; j < 2; ++j) h3[g * 2 + j][c] = fmaxf(acc[j] + bv, 0.f);
    }
    __syncthreads();

    {
        const int row = t >> 4, sub = t & 15;
        float pgv = 0.f;
#pragma unroll
        for (int k = 0; k < 8; ++k) {
            const int c = sub + 16 * k;
            pgv += h0[row][c] * h0[row][128 + c] * ow[c];
        }
        const float phv = h3[row][sub]      * ow[128 + sub]
                        + h3[row][sub + 16] * ow[144 + sub];
        pg[row][sub] = pgv; ph[row][sub] = phv;
    }
    __syncthreads();
    if (t < 16) {
        float sg = 0.f, sh = 0.f;
#pragma unroll
        for (int k = 0; k < 16; ++k) { sg += pg[t][k]; sh += ph[t][k]; }
        const float z = sg * inv_nunv[t] + sh + ob[0];
        out[bb0 + t] = 1.0f / (1.0f + expf(-z));
    }
}

// ---------------------------------------------------------------------------
// Launch. ws layout (binned path, ~158.8 MB):
//   A[2][N][128]   102.4 MB   (x2 aliases A[0] — safe, see gemm_fused note)
//   x1[N][128]      51.2 MB
//   srec[E] int2     5.12 MB  (dst-sorted packed edges, shared by both layers)
//   bin_start[NBINS+1], cursor[NBINS], hist[NBINS]   ~37.5 KB
// Fallback (ws too small): round-2 memset+global-atomic scatter, 153.6 MB.
// ---------------------------------------------------------------------------
extern "C" void kernel_launch(void* const* d_in, const int* in_sizes, int n_in,
                              void* d_out, int out_size, void* d_ws, size_t ws_size,
                              hipStream_t stream)
{
    const int*   ui      = (const int*)d_in[0];
    const int*   vi      = (const int*)d_in[1];
    const int*   ei      = (const int*)d_in[2];
    const int*   et      = (const int*)d_in[3];
    const float* ew      = (const float*)d_in[4];
    const float* emb     = (const float*)d_in[5];
    const float* w1_rel  = (const float*)d_in[6];
    const float* w1_root = (const float*)d_in[7];
    const float* b1      = (const float*)d_in[8];
    const float* ln_g    = (const float*)d_in[9];
    const float* ln_b    = (const float*)d_in[10];
    const float* w2_rel  = (const float*)d_in[11];
    const float* w2_root = (const float*)d_in[12];
    const float* b2      = (const float*)d_in[13];
    const float* mw0     = (const float*)d_in[14];
    const float* mb0     = (const float*)d_in[15];
    const float* mw1     = (const float*)d_in[16];
    const float* mb1     = (const float*)d_in[17];
    const float* mw2     = (const float*)d_in[18];
    const float* mb2     = (const float*)d_in[19];
    const float* ow      = (const float*)d_in[20];
    const float* ob      = (const float*)d_in[21];
    float* out = (float*)d_out;

    const int N = N_NODES, E = N_EDGES, B = NBATCH;

    float* A  = (float*)d_ws;                      // [2][N][128]
    float* x1 = A  + (size_t)2 * N * EMBD;         // [N][128]
    float* x2 = A;                                 // aliases A[0]

    int2* srec      = (int2*)(x1 + (size_t)N * EMBD);
    int*  bin_start = (int*)(srec + E);
    int*  cursor    = bin_start + (NBINS + 1);
    int*  hist      = cursor + NBINS;

    const size_t need_binned = (size_t)((char*)(hist + NBINS) - (char*)d_ws);

    if (ws_size >= need_binned) {
        // ---- Sort edges by dst bin (once; shared by both layers) ----
        hipMemsetAsync(hist, 0, NBINS * sizeof(int), stream);
        hist_kernel<<<(E + 255) / 256, 256, 0, stream>>>(ei, hist, E);
        scan_kernel<<<1, 1024, 0, stream>>>(hist, bin_start, cursor);
        bucket_kernel<<<(E + 255) / 256, 256, 0, stream>>>(ei, et, ew, cursor, srec, E);

        // ---- Layer 1 ----
        accum_kernel<<<NBINS, 256, 0, stream>>>(emb, srec, bin_start, A, N);
        gemm_fused<<<(N + 63) / 64, 256, 0, stream>>>(
            A, A + (size_t)N * EMBD, emb,
            w1_rel, w1_rel + 128 * 128, w1_root,
            b1, ln_g, ln_b, x1, N, 1);

        // ---- Layer 2 ----
        accum_kernel<<<NBINS, 256, 0, stream>>>(x1, srec, bin_start, A, N);
        gemm_fused<<<(N + 63) / 64, 256, 0, stream>>>(
            A, A + (size_t)N * EMBD, x1,
            w2_rel, w2_rel + 128 * 128, w2_root,
            b2, nullptr, nullptr, x2, N, 0);
    } else {
        // ---- Fallback: round-2 global-atomic path ----
        const size_t abytes = (size_t)2 * N * EMBD * sizeof(float);
        hipMemsetAsync(A, 0, abytes, stream);
        scatter_kernel<<<4096, 256, 0, stream>>>(emb, ei, et, ew, A, E, N);
        gemm_fused<<<(N + 63) / 64, 256, 0, stream>>>(
            A, A + (size_t)N * EMBD, emb,
            w1_rel, w1_rel + 128 * 128, w1_root,
            b1, ln_g, ln_b, x1, N, 1);
        hipMemsetAsync(A, 0, abytes, stream);
        scatter_kernel<<<4096, 256, 0, stream>>>(x1, ei, et, ew, A, E, N);
        gemm_fused<<<(N + 63) / 64, 256, 0, stream>>>(
            A, A + (size_t)N * EMBD, x1,
            w2_rel, w2_rel + 128 * 128, w2_root,
            b2, nullptr, nullptr, x2, N, 0);
    }

    // ---- Head ----
    head_kernel<<<B / 16, 256, 0, stream>>>(
        x2, ui, vi, mw0, mb0, mw1, mb1, mw2, mb2, ow, ob, out, B);
}

// Round 4
// 890.856 us; speedup vs baseline: 1.5940x; 1.5940x over previous
//
#include <hip/hip_runtime.h>
#include <cstddef>
#include <cstdint>

// Problem constants (match reference setup_inputs()).
#define N_NODES 100000
#define N_EDGES 640000
#define EMBD    128
#define NBATCH  16384
#define SCAN_NPT 98   // 1024 threads * 98 >= 100000

// ---------------------------------------------------------------------------
// FALLBACK scatter (round-2 path, used only if ws_size is too small):
// A[r][dst] += ew[e] * x[src], one wave per edge, global fp32 atomics.
// ---------------------------------------------------------------------------
__global__ __launch_bounds__(256) void scatter_kernel(
    const float* __restrict__ x, const int* __restrict__ ei,
    const int* __restrict__ et, const float* __restrict__ ew,
    float* __restrict__ A, int E, int N)
{
    const int lane = threadIdx.x & 63;
    const int wid  = blockIdx.x * (blockDim.x >> 6) + (threadIdx.x >> 6);
    const int nw   = gridDim.x * (blockDim.x >> 6);
    for (int e = wid; e < E; e += nw) {
        const int   src = ei[e];
        const int   dst = ei[E + e];
        const int   r   = et[e];
        const float w   = ew[e];
        const float* xr = x + (size_t)src * EMBD;
        const float v0 = xr[lane]      * w;
        const float v1 = xr[lane + 64] * w;
        float* ar = A + ((size_t)r * N + dst) * EMBD;
        atomicAdd(ar + lane,      v0);
        atomicAdd(ar + lane + 64, v1);
    }
}

// ---------------------------------------------------------------------------
// CSR sort phase 1: per-dst-node histogram (into cursor, zeroed by memset).
// ---------------------------------------------------------------------------
__global__ __launch_bounds__(256) void hist_kernel(
    const int* __restrict__ ei, int* __restrict__ cursor, int E)
{
    const int e = blockIdx.x * 256 + threadIdx.x;
    if (e < E) atomicAdd(&cursor[ei[E + e]], 1);
}

// ---------------------------------------------------------------------------
// Phase 2: in-place exclusive prefix scan of cursor[0..n) (counts -> starts).
// Single 1024-thread block, SCAN_NPT values/thread, two-pass (sum, then
// rewrite) so each element is read and written by the same thread only.
// ---------------------------------------------------------------------------
__global__ __launch_bounds__(1024) void scan_kernel(int* __restrict__ cursor, int n)
{
    __shared__ int part[1024];
    const int t    = threadIdx.x;
    const int base = t * SCAN_NPT;
    int s = 0;
    for (int i = 0; i < SCAN_NPT; ++i) {
        const int idx = base + i;
        if (idx < n) s += cursor[idx];
    }
    part[t] = s;
    __syncthreads();
    for (int off = 1; off < 1024; off <<= 1) {
        const int add = (t >= off) ? part[t - off] : 0;
        __syncthreads();
        part[t] += add;
        __syncthreads();
    }
    int run = (t == 0) ? 0 : part[t - 1];
    for (int i = 0; i < SCAN_NPT; ++i) {
        const int idx = base + i;
        if (idx < n) { const int c = cursor[idx]; cursor[idx] = run; run += c; }
    }
}

// ---------------------------------------------------------------------------
// Phase 3: bucket edges into dst-sorted order. After this kernel,
// cursor[n] == END of node n's run (start = cursor[n-1], or 0 for n==0).
// Record: src (17b) | rel (1b @17) in .x, weight bits in .y.
// ---------------------------------------------------------------------------
__global__ __launch_bounds__(256) void bucket_kernel(
    const int* __restrict__ ei, const int* __restrict__ et,
    const float* __restrict__ ew, int* __restrict__ cursor,
    int2* __restrict__ srec, int E)
{
    const int e = blockIdx.x * 256 + threadIdx.x;
    if (e >= E) return;
    const int src = ei[e];
    const int dst = ei[E + e];
    const int r   = et[e];
    const int pos = atomicAdd(&cursor[dst], 1);
    srec[pos] = make_int2(src | (r << 17), __float_as_int(ew[e]));
}

// ---------------------------------------------------------------------------
// Phase 4: one wave per dst node. Register accumulation of both relations
// (4 VGPRs/lane), 2 gathers in flight, plain coalesced stores — NO atomics.
// Every A row written => no memset of A needed.
// ---------------------------------------------------------------------------
__global__ __launch_bounds__(256) void accum_csr(
    const float* __restrict__ x, const int2* __restrict__ srec,
    const int* __restrict__ cursor, float* __restrict__ A, int N)
{
    const int wid  = blockIdx.x * 4 + (threadIdx.x >> 6);   // dst node
    const int lane = threadIdx.x & 63;
    const int s = (wid == 0) ? 0 : cursor[wid - 1];
    const int e = cursor[wid];

    float a0 = 0.f, a1 = 0.f, b0 = 0.f, b1 = 0.f;
    int i = s;
    for (; i + 1 < e; i += 2) {
        const int2 r0 = srec[i];
        const int2 r1 = srec[i + 1];
        const float* xp = x + (size_t)(r0.x & 0x1FFFF) * EMBD;
        const float* xq = x + (size_t)(r1.x & 0x1FFFF) * EMBD;
        const float w0 = __int_as_float(r0.y);
        const float w1 = __int_as_float(r1.y);
        const float p0 = xp[lane], p1 = xp[lane + 64];
        const float q0 = xq[lane], q1 = xq[lane + 64];
        if (r0.x & (1 << 17)) { b0 += p0 * w0; b1 += p1 * w0; }
        else                  { a0 += p0 * w0; a1 += p1 * w0; }
        if (r1.x & (1 << 17)) { b0 += q0 * w1; b1 += q1 * w1; }
        else                  { a0 += q0 * w1; a1 += q1 * w1; }
    }
    if (i < e) {
        const int2 r0 = srec[i];
        const float* xp = x + (size_t)(r0.x & 0x1FFFF) * EMBD;
        const float w0 = __int_as_float(r0.y);
        const float p0 = xp[lane], p1 = xp[lane + 64];
        if (r0.x & (1 << 17)) { b0 += p0 * w0; b1 += p1 * w0; }
        else                  { a0 += p0 * w0; a1 += p1 * w0; }
    }
    A[(size_t)wid * EMBD + lane]                  = a0;
    A[(size_t)wid * EMBD + lane + 64]             = a1;
    A[((size_t)N + wid) * EMBD + lane]            = b0;
    A[((size_t)N + wid) * EMBD + lane + 64]       = b1;
}

// ---------------------------------------------------------------------------
// Fused GEMM: out[M,128] = S0@W0 + S1@W1 + S2@W2 + bias, optional ReLU+LN.
// Virtual K=384. BM=128, BN=128, BK=32; 256 threads (tx=t&15 cols,
// ty=t>>4 rows), 8x8 micro-tile split as rows {ty*4, 64+ty*4} x cols
// {tx*4, 64+tx*4} so all LDS b128 reads are <=2-way bank-aliased (free).
// Each block reads only rows [m0,m0+128) of S* and writes the same rows of
// out strictly after all reads -> out may alias S0/S1/S2.
// ---------------------------------------------------------------------------
__global__ __launch_bounds__(256) void gemm_fused(
    const float* __restrict__ S0, const float* __restrict__ S1, const float* __restrict__ S2,
    const float* __restrict__ W0, const float* __restrict__ W1, const float* __restrict__ W2,
    const float* __restrict__ bias, const float* __restrict__ lng, const float* __restrict__ lnb,
    float* __restrict__ out, int M, int do_ln)
{
    __shared__ float As[32][132];   // [k][row], stride 132: 16B-aligned rows
    __shared__ float Bs[32][132];   // [k][col]

    const int t  = threadIdx.x;
    const int tx = t & 15, ty = t >> 4;
    const int m0 = blockIdx.x * 128;

    float acc[8][8];
#pragma unroll
    for (int j = 0; j < 8; ++j)
#pragma unroll
        for (int i = 0; i < 8; ++i) acc[j][i] = 0.f;

    const float* Ss[3] = {S0, S1, S2};
    const float* Ws[3] = {W0, W1, W2};

    const int arow = t >> 3;        // 0..31 (4 passes of 32 rows)
    const int akk  = (t & 7) * 4;   // k-slot within 32
    const int brow = t >> 5;        // 0..7 (4 passes of 8 k-rows)
    const int bcol = (t & 31) * 4;

    for (int kc = 0; kc < 12; ++kc) {
        const float* S = Ss[kc >> 2];
        const float* W = Ws[kc >> 2];
        const int koff = (kc & 3) * 32;

#pragma unroll
        for (int p = 0; p < 4; ++p) {           // A tile 128x32, transposed
            const int row = arow + p * 32;
            const int rg  = m0 + row;
            float4 f;
            if (rg < M) f = *(const float4*)(S + (size_t)rg * EMBD + koff + akk);
            else        f = make_float4(0.f, 0.f, 0.f, 0.f);
            As[akk + 0][row] = f.x;
            As[akk + 1][row] = f.y;
            As[akk + 2][row] = f.z;
            As[akk + 3][row] = f.w;
        }
#pragma unroll
        for (int p = 0; p < 4; ++p) {           // B tile 32x128
            const int kr = brow + p * 8;
            float4 f = *(const float4*)(W + (size_t)(koff + kr) * EMBD + bcol);
            *(float4*)&Bs[kr][bcol] = f;
        }
        __syncthreads();

#pragma unroll
        for (int k = 0; k < 32; ++k) {
            const float4 a0 = *(const float4*)&As[k][ty * 4];
            const float4 a1 = *(const float4*)&As[k][64 + ty * 4];
            const float4 b0 = *(const float4*)&Bs[k][tx * 4];
            const float4 b1 = *(const float4*)&Bs[k][64 + tx * 4];
            const float av[8] = {a0.x, a0.y, a0.z, a0.w, a1.x, a1.y, a1.z, a1.w};
            const float bv[8] = {b0.x, b0.y, b0.z, b0.w, b1.x, b1.y, b1.z, b1.w};
#pragma unroll
            for (int j = 0; j < 8; ++j)
#pragma unroll
                for (int i = 0; i < 8; ++i) acc[j][i] += av[j] * bv[i];
        }
        __syncthreads();
    }

    // Epilogue. Thread's cols: c0=tx*4..+3, c1=64+tx*4..+3.
    const float4 bias0 = *(const float4*)(bias + tx * 4);
    const float4 bias1 = *(const float4*)(bias + 64 + tx * 4);
    const float bb[8] = {bias0.x, bias0.y, bias0.z, bias0.w,
                         bias1.x, bias1.y, bias1.z, bias1.w};
    float gg[8], bt[8];
    if (do_ln) {
        const float4 g0 = *(const float4*)(lng + tx * 4);
        const float4 g1 = *(const float4*)(lng + 64 + tx * 4);
        const float4 t0 = *(const float4*)(lnb + tx * 4);
        const float4 t1 = *(const float4*)(lnb + 64 + tx * 4);
        gg[0]=g0.x; gg[1]=g0.y; gg[2]=g0.z; gg[3]=g0.w;
        gg[4]=g1.x; gg[5]=g1.y; gg[6]=g1.z; gg[7]=g1.w;
        bt[0]=t0.x; bt[1]=t0.y; bt[2]=t0.z; bt[3]=t0.w;
        bt[4]=t1.x; bt[5]=t1.y; bt[6]=t1.z; bt[7]=t1.w;
    }
#pragma unroll
    for (int j = 0; j < 8; ++j) {
        const int row = (j < 4) ? (ty * 4 + j) : (64 + ty * 4 + j - 4);
        const int rg  = m0 + row;
        float v[8];
#pragma unroll
        for (int i = 0; i < 8; ++i) v[i] = acc[j][i] + bb[i];
        if (do_ln) {
#pragma unroll
            for (int i = 0; i < 8; ++i) v[i] = fmaxf(v[i], 0.f);
            // Row reduction across the 16 tx lanes (consecutive in wave).
            float s = 0.f, sq = 0.f;
#pragma unroll
            for (int i = 0; i < 8; ++i) { s += v[i]; sq += v[i] * v[i]; }
#pragma unroll
            for (int off = 8; off > 0; off >>= 1) {
                s  += __shfl_xor(s,  off, 16);
                sq += __shfl_xor(sq, off, 16);
            }
            const float mu   = s * (1.0f / 128.0f);
            const float var  = sq * (1.0f / 128.0f) - mu * mu;
            const float rstd = rsqrtf(var + 1e-5f);
#pragma unroll
            for (int i = 0; i < 8; ++i) v[i] = (v[i] - mu) * rstd * gg[i] + bt[i];
        }
        if (rg < M) {
            *(float4*)(out + (size_t)rg * EMBD + tx * 4)      = make_float4(v[0], v[1], v[2], v[3]);
            *(float4*)(out + (size_t)rg * EMBD + 64 + tx * 4) = make_float4(v[4], v[5], v[6], v[7]);
        }
    }
}

// ---------------------------------------------------------------------------
// Fused head: gather u/v, l2 norms, GMF, MLP 256->128->64->32, out proj,
// sigmoid. 16 batch rows per 256-thread block, everything staged in LDS.
// ---------------------------------------------------------------------------
__global__ __launch_bounds__(256) void head_kernel(
    const float* __restrict__ x2, const int* __restrict__ ui, const int* __restrict__ vi,
    const float* __restrict__ mw0, const float* __restrict__ mb0,
    const float* __restrict__ mw1, const float* __restrict__ mb1,
    const float* __restrict__ mw2, const float* __restrict__ mb2,
    const float* __restrict__ ow, const float* __restrict__ ob,
    float* __restrict__ out, int B)
{
    __shared__ float h0[16][256];
    __shared__ float h1[16][128];
    __shared__ float h2[16][64];
    __shared__ float h3[16][32];
    __shared__ float ps_u[16][16], ps_v[16][16];
    __shared__ float inv_nunv[16];
    __shared__ float pg[16][16], ph[16][16];

    const int t   = threadIdx.x;
    const int bb0 = blockIdx.x * 16;

    for (int r = 0; r < 16; ++r) {
        const int b   = bb0 + r;
        const int idx = (t < 128) ? ui[b] : vi[b];
        const int c   = t & 127;
        h0[r][t] = x2[(size_t)idx * EMBD + c];
    }
    __syncthreads();

    {
        const int row = t >> 4, sub = t & 15;
        float su = 0.f, sv = 0.f;
#pragma unroll
        for (int k = 0; k < 8; ++k) {
            const float a = h0[row][sub + 16 * k];       su += a * a;
            const float b = h0[row][128 + sub + 16 * k]; sv += b * b;
        }
        ps_u[row][sub] = su; ps_v[row][sub] = sv;
    }
    __syncthreads();
    if (t < 16) {
        float su = 0.f, sv = 0.f;
#pragma unroll
        for (int k = 0; k < 16; ++k) { su += ps_u[t][k]; sv += ps_v[t][k]; }
        const float nu = fmaxf(sqrtf(su), 1e-12f);
        const float nv = fmaxf(sqrtf(sv), 1e-12f);
        inv_nunv[t] = 1.0f / (nu * nv);
    }
    __syncthreads();

    {
        const int c = t & 127, rr = t >> 7;
        float acc[8];
#pragma unroll
        for (int j = 0; j < 8; ++j) acc[j] = 0.f;
        for (int i = 0; i < 256; i += 4) {
            const float w0 = mw0[(i + 0) * 128 + c];
            const float w1 = mw0[(i + 1) * 128 + c];
            const float w2 = mw0[(i + 2) * 128 + c];
            const float w3 = mw0[(i + 3) * 128 + c];
#pragma unroll
            for (int j = 0; j < 8; ++j) {
                const float4 a = *(const float4*)&h0[rr * 8 + j][i];
                acc[j] += a.x * w0 + a.y * w1 + a.z * w2 + a.w * w3;
            }
        }
        const float bv = mb0[c];
#pragma unroll
        for (int j = 0; j < 8; ++j) h1[rr * 8 + j][c] = fmaxf(acc[j] + bv, 0.f);
    }
    __syncthreads();

    {
        const int c = t & 63, g = t >> 6;
        float acc[4] = {0.f, 0.f, 0.f, 0.f};
        for (int i = 0; i < 128; i += 4) {
            const float w0 = mw1[(i + 0) * 64 + c];
            const float w1 = mw1[(i + 1) * 64 + c];
            const float w2 = mw1[(i + 2) * 64 + c];
            const float w3 = mw1[(i + 3) * 64 + c];
#pragma unroll
            for (int j = 0; j < 4; ++j) {
                const float4 a = *(const float4*)&h1[g * 4 + j][i];
                acc[j] += a.x * w0 + a.y * w1 + a.z * w2 + a.w * w3;
            }
        }
        const float bv = mb1[c];
#pragma unroll
        for (int j = 0; j < 4; ++j) h2[g * 4 + j][c] = fmaxf(acc[j] + bv, 0.f);
    }
    __syncthreads();

    {
        const int c = t & 31, g = t >> 5;
        float acc[2] = {0.f, 0.f};
        for (int i = 0; i < 64; i += 4) {
            const float w0 = mw2[(i + 0) * 32 + c];
            const float w1 = mw2[(i + 1) * 32 + c];
            const float w2 = mw2[(i + 2) * 32 + c];
            const float w3 = mw2[(i + 3) * 32 + c];
#pragma unroll
            for (int j = 0; j < 2; ++j) {
                const float4 a = *(const float4*)&h2[g * 2 + j][i];
                acc[j] += a.x * w0 + a.y * w1 + a.z * w2 + a.w * w3;
            }
        }
        const float bv = mb2[c];
#pragma unroll
        for (int j = 0; j < 2; ++j) h3[g * 2 + j][c] = fmaxf(acc[j] + bv, 0.f);
    }
    __syncthreads();

    {
        const int row = t >> 4, sub = t & 15;
        float pgv = 0.f;
#pragma unroll
        for (int k = 0; k < 8; ++k) {
            const int c = sub + 16 * k;
            pgv += h0[row][c] * h0[row][128 + c] * ow[c];
        }
        const float phv = h3[row][sub]      * ow[128 + sub]
                        + h3[row][sub + 16] * ow[144 + sub];
        pg[row][sub] = pgv; ph[row][sub] = phv;
    }
    __syncthreads();
    if (t < 16) {
        float sg = 0.f, sh = 0.f;
#pragma unroll
        for (int k = 0; k < 16; ++k) { sg += pg[t][k]; sh += ph[t][k]; }
        const float z = sg * inv_nunv[t] + sh + ob[0];
        out[bb0 + t] = 1.0f / (1.0f + expf(-z));
    }
}

// ---------------------------------------------------------------------------
// Launch. ws layout (CSR path, ~159.1 MB):
//   A[2][N][128]   102.4 MB   (x2 aliases A[0] — safe, see gemm_fused note)
//   x1[N][128]      51.2 MB
//   srec[E] int2     5.12 MB  (dst-sorted packed edges, shared by both layers)
//   cursor[N]        0.4 MB   (hist -> scan -> bucket ends, all in place)
// Fallback (ws too small): round-2 memset+global-atomic scatter, 153.6 MB.
// ---------------------------------------------------------------------------
extern "C" void kernel_launch(void* const* d_in, const int* in_sizes, int n_in,
                              void* d_out, int out_size, void* d_ws, size_t ws_size,
                              hipStream_t stream)
{
    const int*   ui      = (const int*)d_in[0];
    const int*   vi      = (const int*)d_in[1];
    const int*   ei      = (const int*)d_in[2];
    const int*   et      = (const int*)d_in[3];
    const float* ew      = (const float*)d_in[4];
    const float* emb     = (const float*)d_in[5];
    const float* w1_rel  = (const float*)d_in[6];
    const float* w1_root = (const float*)d_in[7];
    const float* b1      = (const float*)d_in[8];
    const float* ln_g    = (const float*)d_in[9];
    const float* ln_b    = (const float*)d_in[10];
    const float* w2_rel  = (const float*)d_in[11];
    const float* w2_root = (const float*)d_in[12];
    const float* b2      = (const float*)d_in[13];
    const float* mw0     = (const float*)d_in[14];
    const float* mb0     = (const float*)d_in[15];
    const float* mw1     = (const float*)d_in[16];
    const float* mb1     = (const float*)d_in[17];
    const float* mw2     = (const float*)d_in[18];
    const float* mb2     = (const float*)d_in[19];
    const float* ow      = (const float*)d_in[20];
    const float* ob      = (const float*)d_in[21];
    float* out = (float*)d_out;

    const int N = N_NODES, E = N_EDGES, B = NBATCH;

    float* A  = (float*)d_ws;                      // [2][N][128]
    float* x1 = A  + (size_t)2 * N * EMBD;         // [N][128]
    float* x2 = A;                                 // aliases A[0]

    int2* srec   = (int2*)(x1 + (size_t)N * EMBD);
    int*  cursor = (int*)(srec + E);

    const size_t need_csr = (size_t)((char*)(cursor + N) - (char*)d_ws);

    if (ws_size >= need_csr) {
        // ---- Sort edges by dst node (once; shared by both layers) ----
        hipMemsetAsync(cursor, 0, N * sizeof(int), stream);
        hist_kernel<<<(E + 255) / 256, 256, 0, stream>>>(ei, cursor, E);
        scan_kernel<<<1, 1024, 0, stream>>>(cursor, N);
        bucket_kernel<<<(E + 255) / 256, 256, 0, stream>>>(ei, et, ew, cursor, srec, E);

        // ---- Layer 1 ----
        accum_csr<<<N / 4, 256, 0, stream>>>(emb, srec, cursor, A, N);
        gemm_fused<<<(N + 127) / 128, 256, 0, stream>>>(
            A, A + (size_t)N * EMBD, emb,
            w1_rel, w1_rel + 128 * 128, w1_root,
            b1, ln_g, ln_b, x1, N, 1);

        // ---- Layer 2 ----
        accum_csr<<<N / 4, 256, 0, stream>>>(x1, srec, cursor, A, N);
        gemm_fused<<<(N + 127) / 128, 256, 0, stream>>>(
            A, A + (size_t)N * EMBD, x1,
            w2_rel, w2_rel + 128 * 128, w2_root,
            b2, nullptr, nullptr, x2, N, 0);
    } else {
        // ---- Fallback: round-2 global-atomic path ----
        const size_t abytes = (size_t)2 * N * EMBD * sizeof(float);
        hipMemsetAsync(A, 0, abytes, stream);
        scatter_kernel<<<4096, 256, 0, stream>>>(emb, ei, et, ew, A, E, N);
        gemm_fused<<<(N + 127) / 128, 256, 0, stream>>>(
            A, A + (size_t)N * EMBD, emb,
            w1_rel, w1_rel + 128 * 128, w1_root,
            b1, ln_g, ln_b, x1, N, 1);
        hipMemsetAsync(A, 0, abytes, stream);
        scatter_kernel<<<4096, 256, 0, stream>>>(x1, ei, et, ew, A, E, N);
        gemm_fused<<<(N + 127) / 128, 256, 0, stream>>>(
            A, A + (size_t)N * EMBD, x1,
            w2_rel, w2_rel + 128 * 128, w2_root,
            b2, nullptr, nullptr, x2, N, 0);
    }

    // ---- Head ----
    head_kernel<<<B / 16, 256, 0, stream>>>(
        x2, ui, vi, mw0, mb0, mw1, mb1, mw2, mb2, ow, ob, out, B);
}

// Round 5
// 693.133 us; speedup vs baseline: 2.0487x; 1.2853x over previous
//
#include <hip/hip_runtime.h>
#include <cstddef>
#include <cstdint>

// Problem constants (match reference setup_inputs()).
#define N_NODES 100000
#define N_EDGES 640000
#define EMBD    128
#define NBATCH  16384

// Hierarchical scan geometry.
#define CHUNK   1024
#define NCHUNK  ((N_NODES + CHUNK - 1) / CHUNK)   // 98

// ---------------------------------------------------------------------------
// FALLBACK scatter (round-2 path, used only if ws_size is too small):
// A[r][dst] += ew[e] * x[src], one wave per edge, global fp32 atomics.
// ---------------------------------------------------------------------------
__global__ __launch_bounds__(256) void scatter_kernel(
    const float* __restrict__ x, const int* __restrict__ ei,
    const int* __restrict__ et, const float* __restrict__ ew,
    float* __restrict__ A, int E, int N)
{
    const int lane = threadIdx.x & 63;
    const int wid  = blockIdx.x * (blockDim.x >> 6) + (threadIdx.x >> 6);
    const int nw   = gridDim.x * (blockDim.x >> 6);
    for (int e = wid; e < E; e += nw) {
        const int   src = ei[e];
        const int   dst = ei[E + e];
        const int   r   = et[e];
        const float w   = ew[e];
        const float* xr = x + (size_t)src * EMBD;
        const float v0 = xr[lane]      * w;
        const float v1 = xr[lane + 64] * w;
        float* ar = A + ((size_t)r * N + dst) * EMBD;
        atomicAdd(ar + lane,      v0);
        atomicAdd(ar + lane + 64, v1);
    }
}

// ---------------------------------------------------------------------------
// CSR sort phase 1: per-dst-node histogram (into cursor, zeroed by memset).
// ---------------------------------------------------------------------------
__global__ __launch_bounds__(256) void hist_kernel(
    const int* __restrict__ ei, int* __restrict__ cursor, int E)
{
    const int e = blockIdx.x * 256 + threadIdx.x;
    if (e < E) atomicAdd(&cursor[ei[E + e]], 1);
}

// ---------------------------------------------------------------------------
// Phase 2a: per-chunk exclusive scan (in place) + chunk total to bsum.
// 98 blocks x 256 threads, 4 elements/thread. (Replaces the round-4
// single-block scan that ran 196 us at 0.16% occupancy.)
// ---------------------------------------------------------------------------
__global__ __launch_bounds__(256) void scan_local(
    int* __restrict__ cursor, int* __restrict__ bsum, int n)
{
    __shared__ int part[256];
    const int t    = threadIdx.x;
    const int base = blockIdx.x * CHUNK + t * 4;
    int v[4];
    int s = 0;
#pragma unroll
    for (int i = 0; i < 4; ++i) {
        const int idx = base + i;
        v[i] = (idx < n) ? cursor[idx] : 0;
        s += v[i];
    }
    part[t] = s;
    __syncthreads();
    for (int off = 1; off < 256; off <<= 1) {
        const int add = (t >= off) ? part[t - off] : 0;
        __syncthreads();
        part[t] += add;
        __syncthreads();
    }
    if (t == 255) bsum[blockIdx.x] = part[255];
    int run = (t == 0) ? 0 : part[t - 1];
#pragma unroll
    for (int i = 0; i < 4; ++i) {
        const int idx = base + i;
        if (idx < n) { cursor[idx] = run; run += v[i]; }
    }
}

// ---------------------------------------------------------------------------
// Phase 2b: exclusive scan of the 98 chunk totals (1 tiny block).
// ---------------------------------------------------------------------------
__global__ __launch_bounds__(128) void scan_bsum(int* __restrict__ bsum)
{
    __shared__ int part[128];
    const int t = threadIdx.x;
    const int v = (t < NCHUNK) ? bsum[t] : 0;
    part[t] = v;
    __syncthreads();
    for (int off = 1; off < 128; off <<= 1) {
        const int add = (t >= off) ? part[t - off] : 0;
        __syncthreads();
        part[t] += add;
        __syncthreads();
    }
    if (t < NCHUNK) bsum[t] = part[t] - v;    // exclusive
}

// ---------------------------------------------------------------------------
// Phase 2c: add chunk offsets -> cursor holds global exclusive prefix sums.
// ---------------------------------------------------------------------------
__global__ __launch_bounds__(256) void scan_add(
    int* __restrict__ cursor, const int* __restrict__ bsum, int n)
{
    const int off  = bsum[blockIdx.x];
    const int base = blockIdx.x * CHUNK + threadIdx.x * 4;
#pragma unroll
    for (int i = 0; i < 4; ++i) {
        const int idx = base + i;
        if (idx < n) cursor[idx] += off;
    }
}

// ---------------------------------------------------------------------------
// Phase 3: bucket edges into dst-sorted order. After this kernel,
// cursor[n] == END of node n's run (start = cursor[n-1], or 0 for n==0).
// Record: src (17b) | rel (1b @17) in .x, weight bits in .y.
// ---------------------------------------------------------------------------
__global__ __launch_bounds__(256) void bucket_kernel(
    const int* __restrict__ ei, const int* __restrict__ et,
    const float* __restrict__ ew, int* __restrict__ cursor,
    int2* __restrict__ srec, int E)
{
    const int e = blockIdx.x * 256 + threadIdx.x;
    if (e >= E) return;
    const int src = ei[e];
    const int dst = ei[E + e];
    const int r   = et[e];
    const int pos = atomicAdd(&cursor[dst], 1);
    srec[pos] = make_int2(src | (r << 17), __float_as_int(ew[e]));
}

// ---------------------------------------------------------------------------
// Phase 4: one wave per dst node. float2 gathers (one dwordx2/lane/edge,
// lane holds dims {2l,2l+1}), 4 gathers in flight, register accumulation of
// both relations, plain coalesced float2 stores — NO atomics.
// Every A row written => no memset of A needed.
// ---------------------------------------------------------------------------
__global__ __launch_bounds__(256) void accum_csr(
    const float* __restrict__ x, const int2* __restrict__ srec,
    const int* __restrict__ cursor, float* __restrict__ A, int N)
{
    const int wid  = blockIdx.x * 4 + (threadIdx.x >> 6);   // dst node
    const int lane = threadIdx.x & 63;
    const int s = (wid == 0) ? 0 : cursor[wid - 1];
    const int e = cursor[wid];

    float2 a = make_float2(0.f, 0.f), b = make_float2(0.f, 0.f);
    int i = s;
    for (; i + 3 < e; i += 4) {
        const int2 r0 = srec[i];
        const int2 r1 = srec[i + 1];
        const int2 r2 = srec[i + 2];
        const int2 r3 = srec[i + 3];
        const float2 p0 = ((const float2*)(x + (size_t)(r0.x & 0x1FFFF) * EMBD))[lane];
        const float2 p1 = ((const float2*)(x + (size_t)(r1.x & 0x1FFFF) * EMBD))[lane];
        const float2 p2 = ((const float2*)(x + (size_t)(r2.x & 0x1FFFF) * EMBD))[lane];
        const float2 p3 = ((const float2*)(x + (size_t)(r3.x & 0x1FFFF) * EMBD))[lane];
        const float w0 = __int_as_float(r0.y);
        const float w1 = __int_as_float(r1.y);
        const float w2 = __int_as_float(r2.y);
        const float w3 = __int_as_float(r3.y);
        if (r0.x & (1 << 17)) { b.x += p0.x * w0; b.y += p0.y * w0; }
        else                  { a.x += p0.x * w0; a.y += p0.y * w0; }
        if (r1.x & (1 << 17)) { b.x += p1.x * w1; b.y += p1.y * w1; }
        else                  { a.x += p1.x * w1; a.y += p1.y * w1; }
        if (r2.x & (1 << 17)) { b.x += p2.x * w2; b.y += p2.y * w2; }
        else                  { a.x += p2.x * w2; a.y += p2.y * w2; }
        if (r3.x & (1 << 17)) { b.x += p3.x * w3; b.y += p3.y * w3; }
        else                  { a.x += p3.x * w3; a.y += p3.y * w3; }
    }
    for (; i < e; ++i) {
        const int2 r0 = srec[i];
        const float2 p0 = ((const float2*)(x + (size_t)(r0.x & 0x1FFFF) * EMBD))[lane];
        const float w0 = __int_as_float(r0.y);
        if (r0.x & (1 << 17)) { b.x += p0.x * w0; b.y += p0.y * w0; }
        else                  { a.x += p0.x * w0; a.y += p0.y * w0; }
    }
    ((float2*)(A + (size_t)wid * EMBD))[lane]           = a;
    ((float2*)(A + ((size_t)N + wid) * EMBD))[lane]     = b;
}

// ---------------------------------------------------------------------------
// Fused GEMM: out[M,128] = S0@W0 + S1@W1 + S2@W2 + bias, optional ReLU+LN.
// Virtual K=384. BM=128, BN=128, BK=32; 256 threads (tx=t&15 cols,
// ty=t>>4 rows), 8x8 micro-tile split as rows {ty*4, 64+ty*4} x cols
// {tx*4, 64+tx*4} so all LDS b128 reads are <=2-way bank-aliased (free).
// Each block reads only rows [m0,m0+128) of S* and writes the same rows of
// out strictly after all reads -> out may alias S0/S1/S2.
// ---------------------------------------------------------------------------
__global__ __launch_bounds__(256) void gemm_fused(
    const float* __restrict__ S0, const float* __restrict__ S1, const float* __restrict__ S2,
    const float* __restrict__ W0, const float* __restrict__ W1, const float* __restrict__ W2,
    const float* __restrict__ bias, const float* __restrict__ lng, const float* __restrict__ lnb,
    float* __restrict__ out, int M, int do_ln)
{
    __shared__ float As[32][132];   // [k][row], stride 132: 16B-aligned rows
    __shared__ float Bs[32][132];   // [k][col]

    const int t  = threadIdx.x;
    const int tx = t & 15, ty = t >> 4;
    const int m0 = blockIdx.x * 128;

    float acc[8][8];
#pragma unroll
    for (int j = 0; j < 8; ++j)
#pragma unroll
        for (int i = 0; i < 8; ++i) acc[j][i] = 0.f;

    const float* Ss[3] = {S0, S1, S2};
    const float* Ws[3] = {W0, W1, W2};

    const int arow = t >> 3;        // 0..31 (4 passes of 32 rows)
    const int akk  = (t & 7) * 4;   // k-slot within 32
    const int brow = t >> 5;        // 0..7 (4 passes of 8 k-rows)
    const int bcol = (t & 31) * 4;

    for (int kc = 0; kc < 12; ++kc) {
        const float* S = Ss[kc >> 2];
        const float* W = Ws[kc >> 2];
        const int koff = (kc & 3) * 32;

#pragma unroll
        for (int p = 0; p < 4; ++p) {           // A tile 128x32, transposed
            const int row = arow + p * 32;
            const int rg  = m0 + row;
            float4 f;
            if (rg < M) f = *(const float4*)(S + (size_t)rg * EMBD + koff + akk);
            else        f = make_float4(0.f, 0.f, 0.f, 0.f);
            As[akk + 0][row] = f.x;
            As[akk + 1][row] = f.y;
            As[akk + 2][row] = f.z;
            As[akk + 3][row] = f.w;
        }
#pragma unroll
        for (int p = 0; p < 4; ++p) {           // B tile 32x128
            const int kr = brow + p * 8;
            float4 f = *(const float4*)(W + (size_t)(koff + kr) * EMBD + bcol);
            *(float4*)&Bs[kr][bcol] = f;
        }
        __syncthreads();

#pragma unroll
        for (int k = 0; k < 32; ++k) {
            const float4 a0 = *(const float4*)&As[k][ty * 4];
            const float4 a1 = *(const float4*)&As[k][64 + ty * 4];
            const float4 b0 = *(const float4*)&Bs[k][tx * 4];
            const float4 b1 = *(const float4*)&Bs[k][64 + tx * 4];
            const float av[8] = {a0.x, a0.y, a0.z, a0.w, a1.x, a1.y, a1.z, a1.w};
            const float bv[8] = {b0.x, b0.y, b0.z, b0.w, b1.x, b1.y, b1.z, b1.w};
#pragma unroll
            for (int j = 0; j < 8; ++j)
#pragma unroll
                for (int i = 0; i < 8; ++i) acc[j][i] += av[j] * bv[i];
        }
        __syncthreads();
    }

    // Epilogue. Thread's cols: c0=tx*4..+3, c1=64+tx*4..+3.
    const float4 bias0 = *(const float4*)(bias + tx * 4);
    const float4 bias1 = *(const float4*)(bias + 64 + tx * 4);
    const float bb[8] = {bias0.x, bias0.y, bias0.z, bias0.w,
                         bias1.x, bias1.y, bias1.z, bias1.w};
    float gg[8], bt[8];
    if (do_ln) {
        const float4 g0 = *(const float4*)(lng + tx * 4);
        const float4 g1 = *(const float4*)(lng + 64 + tx * 4);
        const float4 t0 = *(const float4*)(lnb + tx * 4);
        const float4 t1 = *(const float4*)(lnb + 64 + tx * 4);
        gg[0]=g0.x; gg[1]=g0.y; gg[2]=g0.z; gg[3]=g0.w;
        gg[4]=g1.x; gg[5]=g1.y; gg[6]=g1.z; gg[7]=g1.w;
        bt[0]=t0.x; bt[1]=t0.y; bt[2]=t0.z; bt[3]=t0.w;
        bt[4]=t1.x; bt[5]=t1.y; bt[6]=t1.z; bt[7]=t1.w;
    }
#pragma unroll
    for (int j = 0; j < 8; ++j) {
        const int row = (j < 4) ? (ty * 4 + j) : (64 + ty * 4 + j - 4);
        const int rg  = m0 + row;
        float v[8];
#pragma unroll
        for (int i = 0; i < 8; ++i) v[i] = acc[j][i] + bb[i];
        if (do_ln) {
#pragma unroll
            for (int i = 0; i < 8; ++i) v[i] = fmaxf(v[i], 0.f);
            // Row reduction across the 16 tx lanes (consecutive in wave).
            float s = 0.f, sq = 0.f;
#pragma unroll
            for (int i = 0; i < 8; ++i) { s += v[i]; sq += v[i] * v[i]; }
#pragma unroll
            for (int off = 8; off > 0; off >>= 1) {
                s  += __shfl_xor(s,  off, 16);
                sq += __shfl_xor(sq, off, 16);
            }
            const float mu   = s * (1.0f / 128.0f);
            const float var  = sq * (1.0f / 128.0f) - mu * mu;
            const float rstd = rsqrtf(var + 1e-5f);
#pragma unroll
            for (int i = 0; i < 8; ++i) v[i] = (v[i] - mu) * rstd * gg[i] + bt[i];
        }
        if (rg < M) {
            *(float4*)(out + (size_t)rg * EMBD + tx * 4)      = make_float4(v[0], v[1], v[2], v[3]);
            *(float4*)(out + (size_t)rg * EMBD + 64 + tx * 4) = make_float4(v[4], v[5], v[6], v[7]);
        }
    }
}

// ---------------------------------------------------------------------------
// Fused head: gather u/v, l2 norms, GMF, MLP 256->128->64->32, out proj,
// sigmoid. 16 batch rows per 256-thread block, everything staged in LDS.
// ---------------------------------------------------------------------------
__global__ __launch_bounds__(256) void head_kernel(
    const float* __restrict__ x2, const int* __restrict__ ui, const int* __restrict__ vi,
    const float* __restrict__ mw0, const float* __restrict__ mb0,
    const float* __restrict__ mw1, const float* __restrict__ mb1,
    const float* __restrict__ mw2, const float* __restrict__ mb2,
    const float* __restrict__ ow, const float* __restrict__ ob,
    float* __restrict__ out, int B)
{
    __shared__ float h0[16][256];
    __shared__ float h1[16][128];
    __shared__ float h2[16][64];
    __shared__ float h3[16][32];
    __shared__ float ps_u[16][16], ps_v[16][16];
    __shared__ float inv_nunv[16];
    __shared__ float pg[16][16], ph[16][16];

    const int t   = threadIdx.x;
    const int bb0 = blockIdx.x * 16;

    for (int r = 0; r < 16; ++r) {
        const int b   = bb0 + r;
        const int idx = (t < 128) ? ui[b] : vi[b];
        const int c   = t & 127;
        h0[r][t] = x2[(size_t)idx * EMBD + c];
    }
    __syncthreads();

    {
        const int row = t >> 4, sub = t & 15;
        float su = 0.f, sv = 0.f;
#pragma unroll
        for (int k = 0; k < 8; ++k) {
            const float a = h0[row][sub + 16 * k];       su += a * a;
            const float b = h0[row][128 + sub + 16 * k]; sv += b * b;
        }
        ps_u[row][sub] = su; ps_v[row][sub] = sv;
    }
    __syncthreads();
    if (t < 16) {
        float su = 0.f, sv = 0.f;
#pragma unroll
        for (int k = 0; k < 16; ++k) { su += ps_u[t][k]; sv += ps_v[t][k]; }
        const float nu = fmaxf(sqrtf(su), 1e-12f);
        const float nv = fmaxf(sqrtf(sv), 1e-12f);
        inv_nunv[t] = 1.0f / (nu * nv);
    }
    __syncthreads();

    {
        const int c = t & 127, rr = t >> 7;
        float acc[8];
#pragma unroll
        for (int j = 0; j < 8; ++j) acc[j] = 0.f;
        for (int i = 0; i < 256; i += 4) {
            const float w0 = mw0[(i + 0) * 128 + c];
            const float w1 = mw0[(i + 1) * 128 + c];
            const float w2 = mw0[(i + 2) * 128 + c];
            const float w3 = mw0[(i + 3) * 128 + c];
#pragma unroll
            for (int j = 0; j < 8; ++j) {
                const float4 a = *(const float4*)&h0[rr * 8 + j][i];
                acc[j] += a.x * w0 + a.y * w1 + a.z * w2 + a.w * w3;
            }
        }
        const float bv = mb0[c];
#pragma unroll
        for (int j = 0; j < 8; ++j) h1[rr * 8 + j][c] = fmaxf(acc[j] + bv, 0.f);
    }
    __syncthreads();

    {
        const int c = t & 63, g = t >> 6;
        float acc[4] = {0.f, 0.f, 0.f, 0.f};
        for (int i = 0; i < 128; i += 4) {
            const float w0 = mw1[(i + 0) * 64 + c];
            const float w1 = mw1[(i + 1) * 64 + c];
            const float w2 = mw1[(i + 2) * 64 + c];
            const float w3 = mw1[(i + 3) * 64 + c];
#pragma unroll
            for (int j = 0; j < 4; ++j) {
                const float4 a = *(const float4*)&h1[g * 4 + j][i];
                acc[j] += a.x * w0 + a.y * w1 + a.z * w2 + a.w * w3;
            }
        }
        const float bv = mb1[c];
#pragma unroll
        for (int j = 0; j < 4; ++j) h2[g * 4 + j][c] = fmaxf(acc[j] + bv, 0.f);
    }
    __syncthreads();

    {
        const int c = t & 31, g = t >> 5;
        float acc[2] = {0.f, 0.f};
        for (int i = 0; i < 64; i += 4) {
            const float w0 = mw2[(i + 0) * 32 + c];
            const float w1 = mw2[(i + 1) * 32 + c];
            const float w2 = mw2[(i + 2) * 32 + c];
            const float w3 = mw2[(i + 3) * 32 + c];
#pragma unroll
            for (int j = 0; j < 2; ++j) {
                const float4 a = *(const float4*)&h2[g * 2 + j][i];
                acc[j] += a.x * w0 + a.y * w1 + a.z * w2 + a.w * w3;
            }
        }
        const float bv = mb2[c];
#pragma unroll
        for (int j = 0; j < 2; ++j) h3[g * 2 + j][c] = fmaxf(acc[j] + bv, 0.f);
    }
    __syncthreads();

    {
        const int row = t >> 4, sub = t & 15;
        float pgv = 0.f;
#pragma unroll
        for (int k = 0; k < 8; ++k) {
            const int c = sub + 16 * k;
            pgv += h0[row][c] * h0[row][128 + c] * ow[c];
        }
        const float phv = h3[row][sub]      * ow[128 + sub]
                        + h3[row][sub + 16] * ow[144 + sub];
        pg[row][sub] = pgv; ph[row][sub] = phv;
    }
    __syncthreads();
    if (t < 16) {
        float sg = 0.f, sh = 0.f;
#pragma unroll
        for (int k = 0; k < 16; ++k) { sg += pg[t][k]; sh += ph[t][k]; }
        const float z = sg * inv_nunv[t] + sh + ob[0];
        out[bb0 + t] = 1.0f / (1.0f + expf(-z));
    }
}

// ---------------------------------------------------------------------------
// Launch. ws layout (CSR path, ~159.1 MB):
//   A[2][N][128]   102.4 MB   (x2 aliases A[0] — safe, see gemm_fused note)
//   x1[N][128]      51.2 MB
//   srec[E] int2     5.12 MB  (dst-sorted packed edges, shared by both layers)
//   cursor[N]        0.4 MB   (hist -> scan -> bucket ends, all in place)
//   bsum[NCHUNK]     ~400 B   (hierarchical-scan chunk totals)
// Fallback (ws too small): round-2 memset+global-atomic scatter, 153.6 MB.
// ---------------------------------------------------------------------------
extern "C" void kernel_launch(void* const* d_in, const int* in_sizes, int n_in,
                              void* d_out, int out_size, void* d_ws, size_t ws_size,
                              hipStream_t stream)
{
    const int*   ui      = (const int*)d_in[0];
    const int*   vi      = (const int*)d_in[1];
    const int*   ei      = (const int*)d_in[2];
    const int*   et      = (const int*)d_in[3];
    const float* ew      = (const float*)d_in[4];
    const float* emb     = (const float*)d_in[5];
    const float* w1_rel  = (const float*)d_in[6];
    const float* w1_root = (const float*)d_in[7];
    const float* b1      = (const float*)d_in[8];
    const float* ln_g    = (const float*)d_in[9];
    const float* ln_b    = (const float*)d_in[10];
    const float* w2_rel  = (const float*)d_in[11];
    const float* w2_root = (const float*)d_in[12];
    const float* b2      = (const float*)d_in[13];
    const float* mw0     = (const float*)d_in[14];
    const float* mb0     = (const float*)d_in[15];
    const float* mw1     = (const float*)d_in[16];
    const float* mb1     = (const float*)d_in[17];
    const float* mw2     = (const float*)d_in[18];
    const float* mb2     = (const float*)d_in[19];
    const float* ow      = (const float*)d_in[20];
    const float* ob      = (const float*)d_in[21];
    float* out = (float*)d_out;

    const int N = N_NODES, E = N_EDGES, B = NBATCH;

    float* A  = (float*)d_ws;                      // [2][N][128]
    float* x1 = A  + (size_t)2 * N * EMBD;         // [N][128]
    float* x2 = A;                                 // aliases A[0]

    int2* srec   = (int2*)(x1 + (size_t)N * EMBD);
    int*  cursor = (int*)(srec + E);
    int*  bsum   = cursor + N;

    const size_t need_csr = (size_t)((char*)(bsum + NCHUNK) - (char*)d_ws);

    if (ws_size >= need_csr) {
        // ---- Sort edges by dst node (once; shared by both layers) ----
        hipMemsetAsync(cursor, 0, N * sizeof(int), stream);
        hist_kernel<<<(E + 255) / 256, 256, 0, stream>>>(ei, cursor, E);
        scan_local<<<NCHUNK, 256, 0, stream>>>(cursor, bsum, N);
        scan_bsum<<<1, 128, 0, stream>>>(bsum);
        scan_add<<<NCHUNK, 256, 0, stream>>>(cursor, bsum, N);
        bucket_kernel<<<(E + 255) / 256, 256, 0, stream>>>(ei, et, ew, cursor, srec, E);

        // ---- Layer 1 ----
        accum_csr<<<N / 4, 256, 0, stream>>>(emb, srec, cursor, A, N);
        gemm_fused<<<(N + 127) / 128, 256, 0, stream>>>(
            A, A + (size_t)N * EMBD, emb,
            w1_rel, w1_rel + 128 * 128, w1_root,
            b1, ln_g, ln_b, x1, N, 1);

        // ---- Layer 2 ----
        accum_csr<<<N / 4, 256, 0, stream>>>(x1, srec, cursor, A, N);
        gemm_fused<<<(N + 127) / 128, 256, 0, stream>>>(
            A, A + (size_t)N * EMBD, x1,
            w2_rel, w2_rel + 128 * 128, w2_root,
            b2, nullptr, nullptr, x2, N, 0);
    } else {
        // ---- Fallback: round-2 global-atomic path ----
        const size_t abytes = (size_t)2 * N * EMBD * sizeof(float);
        hipMemsetAsync(A, 0, abytes, stream);
        scatter_kernel<<<4096, 256, 0, stream>>>(emb, ei, et, ew, A, E, N);
        gemm_fused<<<(N + 127) / 128, 256, 0, stream>>>(
            A, A + (size_t)N * EMBD, emb,
            w1_rel, w1_rel + 128 * 128, w1_root,
            b1, ln_g, ln_b, x1, N, 1);
        hipMemsetAsync(A, 0, abytes, stream);
        scatter_kernel<<<4096, 256, 0, stream>>>(x1, ei, et, ew, A, E, N);
        gemm_fused<<<(N + 127) / 128, 256, 0, stream>>>(
            A, A + (size_t)N * EMBD, x1,
            w2_rel, w2_rel + 128 * 128, w2_root,
            b2, nullptr, nullptr, x2, N, 0);
    }

    // ---- Head ----
    head_kernel<<<B / 16, 256, 0, stream>>>(
        x2, ui, vi, mw0, mb0, mw1, mb1, mw2, mb2, ow, ob, out, B);
}

// Round 6
// 501.240 us; speedup vs baseline: 2.8330x; 1.3828x over previous
//
#include <hip/hip_runtime.h>
#include <cstddef>
#include <cstdint>

// Problem constants (match reference setup_inputs()).
#define N_NODES 100000
#define N_EDGES 640000
#define EMBD    128
#define NBATCH  16384
#define CHUNK   1024
#define NCHUNK  ((N_NODES + CHUNK - 1) / CHUNK)   // 98

// MFMA fragment types (guide §3: bf16 16x16x32 -> short8 / float4).
typedef short bf16x8 __attribute__((ext_vector_type(8)));
typedef float f32x4  __attribute__((ext_vector_type(4)));

// ---------------------------------------------------------------------------
// Split-bf16 packing: uint32 = bf16(x) [hi16] | bf16(x - hi) [lo16], RNE both.
// Value round-trips with ~2^-17 relative error; a*b via 3 MFMAs drops only
// the lo*lo term (~2^-18 relative).
// ---------------------------------------------------------------------------
__device__ __forceinline__ unsigned pack_split(float x) {
    unsigned u  = __float_as_uint(x);
    unsigned hi = (u + 0x7fffu + ((u >> 16) & 1u)) & 0xffff0000u;
    float    lo = x - __uint_as_float(hi);
    unsigned ul = __float_as_uint(lo);
    unsigned lw = ((ul + 0x7fffu + ((ul >> 16) & 1u)) >> 16) & 0xffffu;
    return hi | lw;
}
__device__ __forceinline__ float unpack_split(unsigned u) {
    return __uint_as_float(u & 0xffff0000u) + __uint_as_float(u << 16);
}

__global__ __launch_bounds__(256) void pack_kernel(
    const float* __restrict__ in, unsigned* __restrict__ out, int n)
{
    const int i = blockIdx.x * 256 + threadIdx.x;
    if (i < n) out[i] = pack_split(in[i]);
}

// ---------------------------------------------------------------------------
// CSR sort phase 1: per-dst-node histogram (into cursor, zeroed by memset).
// ---------------------------------------------------------------------------
__global__ __launch_bounds__(256) void hist_kernel(
    const int* __restrict__ ei, int* __restrict__ cursor, int E)
{
    const int e = blockIdx.x * 256 + threadIdx.x;
    if (e < E) atomicAdd(&cursor[ei[E + e]], 1);
}

// ---------------------------------------------------------------------------
// Phase 2a/b/c: hierarchical exclusive scan (counts -> starts), in place.
// ---------------------------------------------------------------------------
__global__ __launch_bounds__(256) void scan_local(
    int* __restrict__ cursor, int* __restrict__ bsum, int n)
{
    __shared__ int part[256];
    const int t    = threadIdx.x;
    const int base = blockIdx.x * CHUNK + t * 4;
    int v[4];
    int s = 0;
#pragma unroll
    for (int i = 0; i < 4; ++i) {
        const int idx = base + i;
        v[i] = (idx < n) ? cursor[idx] : 0;
        s += v[i];
    }
    part[t] = s;
    __syncthreads();
    for (int off = 1; off < 256; off <<= 1) {
        const int add = (t >= off) ? part[t - off] : 0;
        __syncthreads();
        part[t] += add;
        __syncthreads();
    }
    if (t == 255) bsum[blockIdx.x] = part[255];
    int run = (t == 0) ? 0 : part[t - 1];
#pragma unroll
    for (int i = 0; i < 4; ++i) {
        const int idx = base + i;
        if (idx < n) { cursor[idx] = run; run += v[i]; }
    }
}

__global__ __launch_bounds__(128) void scan_bsum(int* __restrict__ bsum)
{
    __shared__ int part[128];
    const int t = threadIdx.x;
    const int v = (t < NCHUNK) ? bsum[t] : 0;
    part[t] = v;
    __syncthreads();
    for (int off = 1; off < 128; off <<= 1) {
        const int add = (t >= off) ? part[t - off] : 0;
        __syncthreads();
        part[t] += add;
        __syncthreads();
    }
    if (t < NCHUNK) bsum[t] = part[t] - v;    // exclusive
}

__global__ __launch_bounds__(256) void scan_add(
    int* __restrict__ cursor, const int* __restrict__ bsum, int n)
{
    const int off  = bsum[blockIdx.x];
    const int base = blockIdx.x * CHUNK + threadIdx.x * 4;
#pragma unroll
    for (int i = 0; i < 4; ++i) {
        const int idx = base + i;
        if (idx < n) cursor[idx] += off;
    }
}

// ---------------------------------------------------------------------------
// Phase 3: bucket edges into dst-sorted order. After this kernel,
// cursor[n] == END of node n's run (start = cursor[n-1], or 0 for n==0).
// Record: src (17b) | rel (1b @17) in .x, weight bits in .y.
// ---------------------------------------------------------------------------
__global__ __launch_bounds__(256) void bucket_kernel(
    const int* __restrict__ ei, const int* __restrict__ et,
    const float* __restrict__ ew, int* __restrict__ cursor,
    int2* __restrict__ srec, int E)
{
    const int e = blockIdx.x * 256 + threadIdx.x;
    if (e >= E) return;
    const int src = ei[e];
    const int dst = ei[E + e];
    const int r   = et[e];
    const int pos = atomicAdd(&cursor[dst], 1);
    srec[pos] = make_int2(src | (r << 17), __float_as_int(ew[e]));
}

// ---------------------------------------------------------------------------
// Phase 4: one wave per dst node. Gathers PACKED split-bf16 rows (uint2 per
// lane = dims {2l,2l+1}), fp32 register accumulation, stores packed A rows.
// No atomics; every A row written.
// ---------------------------------------------------------------------------
__global__ __launch_bounds__(256) void accum_csr(
    const unsigned* __restrict__ xp, const int2* __restrict__ srec,
    const int* __restrict__ cursor, unsigned* __restrict__ Ap, int N)
{
    const int wid  = blockIdx.x * 4 + (threadIdx.x >> 6);   // dst node
    const int lane = threadIdx.x & 63;
    const int s = (wid == 0) ? 0 : cursor[wid - 1];
    const int e = cursor[wid];

    float ax = 0.f, ay = 0.f, bx = 0.f, by = 0.f;
    int i = s;
    for (; i + 3 < e; i += 4) {
        const int2 r0 = srec[i];
        const int2 r1 = srec[i + 1];
        const int2 r2 = srec[i + 2];
        const int2 r3 = srec[i + 3];
        const uint2 g0 = ((const uint2*)(xp + (size_t)(r0.x & 0x1FFFF) * EMBD))[lane];
        const uint2 g1 = ((const uint2*)(xp + (size_t)(r1.x & 0x1FFFF) * EMBD))[lane];
        const uint2 g2 = ((const uint2*)(xp + (size_t)(r2.x & 0x1FFFF) * EMBD))[lane];
        const uint2 g3 = ((const uint2*)(xp + (size_t)(r3.x & 0x1FFFF) * EMBD))[lane];
        const float w0 = __int_as_float(r0.y);
        const float w1 = __int_as_float(r1.y);
        const float w2 = __int_as_float(r2.y);
        const float w3 = __int_as_float(r3.y);
        {
            const float vx = unpack_split(g0.x), vy = unpack_split(g0.y);
            if (r0.x & (1 << 17)) { bx += vx * w0; by += vy * w0; }
            else                  { ax += vx * w0; ay += vy * w0; }
        }
        {
            const float vx = unpack_split(g1.x), vy = unpack_split(g1.y);
            if (r1.x & (1 << 17)) { bx += vx * w1; by += vy * w1; }
            else                  { ax += vx * w1; ay += vy * w1; }
        }
        {
            const float vx = unpack_split(g2.x), vy = unpack_split(g2.y);
            if (r2.x & (1 << 17)) { bx += vx * w2; by += vy * w2; }
            else                  { ax += vx * w2; ay += vy * w2; }
        }
        {
            const float vx = unpack_split(g3.x), vy = unpack_split(g3.y);
            if (r3.x & (1 << 17)) { bx += vx * w3; by += vy * w3; }
            else                  { ax += vx * w3; ay += vy * w3; }
        }
    }
    for (; i < e; ++i) {
        const int2 r0 = srec[i];
        const uint2 g0 = ((const uint2*)(xp + (size_t)(r0.x & 0x1FFFF) * EMBD))[lane];
        const float w0 = __int_as_float(r0.y);
        const float vx = unpack_split(g0.x), vy = unpack_split(g0.y);
        if (r0.x & (1 << 17)) { bx += vx * w0; by += vy * w0; }
        else                  { ax += vx * w0; ay += vy * w0; }
    }
    ((uint2*)(Ap + (size_t)wid * EMBD))[lane]             = make_uint2(pack_split(ax), pack_split(ay));
    ((uint2*)(Ap + ((size_t)N + wid) * EMBD))[lane]       = make_uint2(pack_split(bx), pack_split(by));
}

// ---------------------------------------------------------------------------
// Split-bf16 MFMA GEMM: out[M,128] = (S0|S1|S2)[M,384] @ W[384,128] + bias,
// where S* are PACKED split-bf16 and W is fp32 (split on the fly while
// staging). Each fp32 product uses 3 MFMAs: ah*bh + ah*bl + al*bh.
// BM=128, BN=128, KC=32. 4 waves: wave w -> rows (w&1)*64, cols (w>>1)*64,
// 4x4 grid of 16x16x32 MFMA tiles, acc = 16 x float4 = 64 VGPRs.
// Fragment layouts (m89/m120 verified): A[m=lane&15][k=quad*8+j];
// C/D col=lane&15, row=quad*4+reg.
// LDS rows padded to 80 B so all b128 frag reads are <=2-way bank-aliased.
// Each block reads only rows [m0,m0+128) of S* and writes the same rows of
// out strictly after all its reads -> out may alias any S*.
// do_ln=1: bias+ReLU+LayerNorm, output PACKED split-bf16.
// do_ln=0: bias only, output fp32.
// ---------------------------------------------------------------------------
__global__ __launch_bounds__(256) void gemm_mfma(
    const unsigned* __restrict__ S0, const unsigned* __restrict__ S1,
    const unsigned* __restrict__ S2,
    const float* __restrict__ wrel, const float* __restrict__ wroot,
    const float* __restrict__ bias, const float* __restrict__ lng,
    const float* __restrict__ lnb, void* __restrict__ outv,
    int M, int do_ln)
{
    __shared__ unsigned short AsH[128 * 40], AsL[128 * 40];   // 10 KB each
    __shared__ unsigned short BsH[128 * 40], BsL[128 * 40];   // (row stride 80 B)
    __shared__ float lnbuf[2][128][2];

    const int t    = threadIdx.x;
    const int wave = t >> 6;
    const int lane = t & 63;
    const int q    = lane >> 4;      // quad
    const int n    = lane & 15;
    const int wrow = wave & 1;
    const int wcol = wave >> 1;
    const int m0   = blockIdx.x * 128;

    // Staging coords: A by row halves, B by column.
    const int arow  = t >> 1;        // 0..127
    const int ahalf = t & 1;
    const int bcol  = t & 127;
    const int bkh   = t >> 7;        // 0..1

    f32x4 acc[4][4];
#pragma unroll
    for (int rt = 0; rt < 4; ++rt)
#pragma unroll
        for (int ct = 0; ct < 4; ++ct)
            acc[rt][ct] = (f32x4){0.f, 0.f, 0.f, 0.f};

    for (int kc = 0; kc < 12; ++kc) {
        const unsigned* Sp  = (kc < 4) ? S0 : (kc < 8) ? S1 : S2;
        const int koff      = (kc & 3) * 32;
        // Virtual W rows kc*32..kc*32+31: rows 0-255 = w_rel flat, 256-383 = w_root.
        const float* Wsrc   = (kc < 8) ? (wrel + (size_t)kc * 32 * EMBD)
                                       : (wroot + (size_t)(kc - 8) * 32 * EMBD);

        __syncthreads();   // previous chunk's frag reads done before overwrite

        // ---- A stage: 128x32 packed, split to AsH/AsL ----
        {
            const int rg = m0 + arow;
            uint4 u[4];
            if (rg < M) {
                const unsigned* p = Sp + (size_t)rg * EMBD + koff + ahalf * 16;
                u[0] = *(const uint4*)(p);
                u[1] = *(const uint4*)(p + 4);
                u[2] = *(const uint4*)(p + 8);
                u[3] = *(const uint4*)(p + 12);
            } else {
                u[0] = u[1] = u[2] = u[3] = make_uint4(0u, 0u, 0u, 0u);
            }
            unsigned* dh = (unsigned*)AsH + arow * 20 + ahalf * 8;
            unsigned* dl = (unsigned*)AsL + arow * 20 + ahalf * 8;
            const unsigned* uu = (const unsigned*)u;
#pragma unroll
            for (int i = 0; i < 8; ++i) {
                const unsigned e0 = uu[2 * i], e1 = uu[2 * i + 1];
                dh[i] = (e1 & 0xffff0000u) | (e0 >> 16);
                dl[i] = (e1 << 16) | (e0 & 0xffffu);
            }
        }
        // ---- B stage: 32x128 fp32 -> transposed split [col][k] ----
        {
            unsigned p[16];
#pragma unroll
            for (int j = 0; j < 16; ++j)
                p[j] = pack_split(Wsrc[(size_t)(bkh * 16 + j) * EMBD + bcol]);
            unsigned* dh = (unsigned*)BsH + bcol * 20 + bkh * 8;
            unsigned* dl = (unsigned*)BsL + bcol * 20 + bkh * 8;
#pragma unroll
            for (int i = 0; i < 8; ++i) {
                const unsigned e0 = p[2 * i], e1 = p[2 * i + 1];
                dh[i] = (e1 & 0xffff0000u) | (e0 >> 16);
                dl[i] = (e1 << 16) | (e0 & 0xffffu);
            }
        }
        __syncthreads();

        // ---- fragments + MFMA ----
        bf16x8 ah[4], al[4], bh[4], bl[4];
#pragma unroll
        for (int rt = 0; rt < 4; ++rt) {
            const int r = wrow * 64 + rt * 16 + n;
            ah[rt] = *(const bf16x8*)&AsH[r * 40 + q * 8];
            al[rt] = *(const bf16x8*)&AsL[r * 40 + q * 8];
        }
#pragma unroll
        for (int ct = 0; ct < 4; ++ct) {
            const int c = wcol * 64 + ct * 16 + n;
            bh[ct] = *(const bf16x8*)&BsH[c * 40 + q * 8];
            bl[ct] = *(const bf16x8*)&BsL[c * 40 + q * 8];
        }
#pragma unroll
        for (int rt = 0; rt < 4; ++rt)
#pragma unroll
            for (int ct = 0; ct < 4; ++ct) {
                acc[rt][ct] = __builtin_amdgcn_mfma_f32_16x16x32_bf16(ah[rt], bh[ct], acc[rt][ct], 0, 0, 0);
                acc[rt][ct] = __builtin_amdgcn_mfma_f32_16x16x32_bf16(ah[rt], bl[ct], acc[rt][ct], 0, 0, 0);
                acc[rt][ct] = __builtin_amdgcn_mfma_f32_16x16x32_bf16(al[rt], bh[ct], acc[rt][ct], 0, 0, 0);
            }
    }

    // ---- epilogue ----
    float bb[4], gg[4], tb[4];
#pragma unroll
    for (int ct = 0; ct < 4; ++ct) {
        const int c = wcol * 64 + ct * 16 + n;
        bb[ct] = bias[c];
        gg[ct] = do_ln ? lng[c] : 0.f;
        tb[ct] = do_ln ? lnb[c] : 0.f;
    }

    if (do_ln) {
        // bias + relu in place; per-row stats via quad shuffle + LDS combine.
#pragma unroll
        for (int rt = 0; rt < 4; ++rt)
#pragma unroll
            for (int r = 0; r < 4; ++r) {
                float s = 0.f, sq = 0.f;
#pragma unroll
                for (int ct = 0; ct < 4; ++ct) {
                    float v = acc[rt][ct][r] + bb[ct];
                    v = fmaxf(v, 0.f);
                    acc[rt][ct][r] = v;
                    s += v; sq += v * v;
                }
#pragma unroll
                for (int off = 1; off < 16; off <<= 1) {
                    s  += __shfl_xor(s,  off, 64);
                    sq += __shfl_xor(sq, off, 64);
                }
                if (n == 0) {
                    const int row = wrow * 64 + rt * 16 + q * 4 + r;
                    lnbuf[wcol][row][0] = s;
                    lnbuf[wcol][row][1] = sq;
                }
            }
        __syncthreads();
        unsigned* outp = (unsigned*)outv;
#pragma unroll
        for (int rt = 0; rt < 4; ++rt)
#pragma unroll
            for (int r = 0; r < 4; ++r) {
                const int row = wrow * 64 + rt * 16 + q * 4 + r;
                const int rg  = m0 + row;
                const float s    = lnbuf[0][row][0] + lnbuf[1][row][0];
                const float sq   = lnbuf[0][row][1] + lnbuf[1][row][1];
                const float mu   = s * (1.0f / 128.0f);
                const float var  = sq * (1.0f / 128.0f) - mu * mu;
                const float rstd = rsqrtf(var + 1e-5f);
                if (rg < M) {
#pragma unroll
                    for (int ct = 0; ct < 4; ++ct) {
                        const int c = wcol * 64 + ct * 16 + n;
                        const float v = (acc[rt][ct][r] - mu) * rstd * gg[ct] + tb[ct];
                        outp[(size_t)rg * EMBD + c] = pack_split(v);
                    }
                }
            }
    } else {
        float* outp = (float*)outv;
#pragma unroll
        for (int rt = 0; rt < 4; ++rt)
#pragma unroll
            for (int r = 0; r < 4; ++r) {
                const int rg = m0 + wrow * 64 + rt * 16 + q * 4 + r;
                if (rg < M) {
#pragma unroll
                    for (int ct = 0; ct < 4; ++ct) {
                        const int c = wcol * 64 + ct * 16 + n;
                        outp[(size_t)rg * EMBD + c] = acc[rt][ct][r] + bb[ct];
                    }
                }
            }
    }
}

// ---------------------------------------------------------------------------
// Fused head: gather u/v, l2 norms, GMF, MLP 256->128->64->32, out proj,
// sigmoid. 16 batch rows per 256-thread block, everything staged in LDS.
// ---------------------------------------------------------------------------
__global__ __launch_bounds__(256) void head_kernel(
    const float* __restrict__ x2, const int* __restrict__ ui, const int* __restrict__ vi,
    const float* __restrict__ mw0, const float* __restrict__ mb0,
    const float* __restrict__ mw1, const float* __restrict__ mb1,
    const float* __restrict__ mw2, const float* __restrict__ mb2,
    const float* __restrict__ ow, const float* __restrict__ ob,
    float* __restrict__ out, int B)
{
    __shared__ float h0[16][256];
    __shared__ float h1[16][128];
    __shared__ float h2[16][64];
    __shared__ float h3[16][32];
    __shared__ float ps_u[16][16], ps_v[16][16];
    __shared__ float inv_nunv[16];
    __shared__ float pg[16][16], ph[16][16];

    const int t   = threadIdx.x;
    const int bb0 = blockIdx.x * 16;

    for (int r = 0; r < 16; ++r) {
        const int b   = bb0 + r;
        const int idx = (t < 128) ? ui[b] : vi[b];
        const int c   = t & 127;
        h0[r][t] = x2[(size_t)idx * EMBD + c];
    }
    __syncthreads();

    {
        const int row = t >> 4, sub = t & 15;
        float su = 0.f, sv = 0.f;
#pragma unroll
        for (int k = 0; k < 8; ++k) {
            const float a = h0[row][sub + 16 * k];       su += a * a;
            const float b = h0[row][128 + sub + 16 * k]; sv += b * b;
        }
        ps_u[row][sub] = su; ps_v[row][sub] = sv;
    }
    __syncthreads();
    if (t < 16) {
        float su = 0.f, sv = 0.f;
#pragma unroll
        for (int k = 0; k < 16; ++k) { su += ps_u[t][k]; sv += ps_v[t][k]; }
        const float nu = fmaxf(sqrtf(su), 1e-12f);
        const float nv = fmaxf(sqrtf(sv), 1e-12f);
        inv_nunv[t] = 1.0f / (nu * nv);
    }
    __syncthreads();

    {
        const int c = t & 127, rr = t >> 7;
        float acc[8];
#pragma unroll
        for (int j = 0; j < 8; ++j) acc[j] = 0.f;
        for (int i = 0; i < 256; i += 4) {
            const float w0 = mw0[(i + 0) * 128 + c];
            const float w1 = mw0[(i + 1) * 128 + c];
            const float w2 = mw0[(i + 2) * 128 + c];
            const float w3 = mw0[(i + 3) * 128 + c];
#pragma unroll
            for (int j = 0; j < 8; ++j) {
                const float4 a = *(const float4*)&h0[rr * 8 + j][i];
                acc[j] += a.x * w0 + a.y * w1 + a.z * w2 + a.w * w3;
            }
        }
        const float bv = mb0[c];
#pragma unroll
        for (int j = 0; j < 8; ++j) h1[rr * 8 + j][c] = fmaxf(acc[j] + bv, 0.f);
    }
    __syncthreads();

    {
        const int c = t & 63, g = t >> 6;
        float acc[4] = {0.f, 0.f, 0.f, 0.f};
        for (int i = 0; i < 128; i += 4) {
            const float w0 = mw1[(i + 0) * 64 + c];
            const float w1 = mw1[(i + 1) * 64 + c];
            const float w2 = mw1[(i + 2) * 64 + c];
            const float w3 = mw1[(i + 3) * 64 + c];
#pragma unroll
            for (int j = 0; j < 4; ++j) {
                const float4 a = *(const float4*)&h1[g * 4 + j][i];
                acc[j] += a.x * w0 + a.y * w1 + a.z * w2 + a.w * w3;
            }
        }
        const float bv = mb1[c];
#pragma unroll
        for (int j = 0; j < 4; ++j) h2[g * 4 + j][c] = fmaxf(acc[j] + bv, 0.f);
    }
    __syncthreads();

    {
        const int c = t & 31, g = t >> 5;
        float acc[2] = {0.f, 0.f};
        for (int i = 0; i < 64; i += 4) {
            const float w0 = mw2[(i + 0) * 32 + c];
            const float w1 = mw2[(i + 1) * 32 + c];
            const float w2 = mw2[(i + 2) * 32 + c];
            const float w3 = mw2[(i + 3) * 32 + c];
#pragma unroll
            for (int j = 0; j < 2; ++j) {
                const float4 a = *(const float4*)&h2[g * 2 + j][i];
                acc[j] += a.x * w0 + a.y * w1 + a.z * w2 + a.w * w3;
            }
        }
        const float bv = mb2[c];
#pragma unroll
        for (int j = 0; j < 2; ++j) h3[g * 2 + j][c] = fmaxf(acc[j] + bv, 0.f);
    }
    __syncthreads();

    {
        const int row = t >> 4, sub = t & 15;
        float pgv = 0.f;
#pragma unroll
        for (int k = 0; k < 8; ++k) {
            const int c = sub + 16 * k;
            pgv += h0[row][c] * h0[row][128 + c] * ow[c];
        }
        const float phv = h3[row][sub]      * ow[128 + sub]
                        + h3[row][sub + 16] * ow[144 + sub];
        pg[row][sub] = pgv; ph[row][sub] = phv;
    }
    __syncthreads();
    if (t < 16) {
        float sg = 0.f, sh = 0.f;
#pragma unroll
        for (int k = 0; k < 16; ++k) { sg += pg[t][k]; sh += ph[t][k]; }
        const float z = sg * inv_nunv[t] + sh + ob[0];
        out[bb0 + t] = 1.0f / (1.0f + expf(-z));
    }
}

// ---------------------------------------------------------------------------
// Launch. ws layout (identical bytes to round 4/5, proven to fit):
//   Ap[2][N][128]  uint32 102.4 MB  (packed split-bf16 aggregates;
//                                    gemm-2 writes fp32 x2 into Ap[0] rows,
//                                    row-aliased safe)
//   xslot[N][128]  uint32  51.2 MB  (packed emb, overwritten row-aliased by
//                                    packed x1 in gemm-1's epilogue)
//   srec[E] int2            5.12 MB
//   cursor[N]               0.4 MB
//   bsum[NCHUNK]            ~400 B
// ---------------------------------------------------------------------------
extern "C" void kernel_launch(void* const* d_in, const int* in_sizes, int n_in,
                              void* d_out, int out_size, void* d_ws, size_t ws_size,
                              hipStream_t stream)
{
    const int*   ui      = (const int*)d_in[0];
    const int*   vi      = (const int*)d_in[1];
    const int*   ei      = (const int*)d_in[2];
    const int*   et      = (const int*)d_in[3];
    const float* ew      = (const float*)d_in[4];
    const float* emb     = (const float*)d_in[5];
    const float* w1_rel  = (const float*)d_in[6];
    const float* w1_root = (const float*)d_in[7];
    const float* b1      = (const float*)d_in[8];
    const float* ln_g    = (const float*)d_in[9];
    const float* ln_b    = (const float*)d_in[10];
    const float* w2_rel  = (const float*)d_in[11];
    const float* w2_root = (const float*)d_in[12];
    const float* b2      = (const float*)d_in[13];
    const float* mw0     = (const float*)d_in[14];
    const float* mb0     = (const float*)d_in[15];
    const float* mw1     = (const float*)d_in[16];
    const float* mb1     = (const float*)d_in[17];
    const float* mw2     = (const float*)d_in[18];
    const float* mb2     = (const float*)d_in[19];
    const float* ow      = (const float*)d_in[20];
    const float* ob      = (const float*)d_in[21];
    float* out = (float*)d_out;

    const int N = N_NODES, E = N_EDGES, B = NBATCH;

    unsigned* Ap    = (unsigned*)d_ws;                 // [2][N][128] packed
    unsigned* xslot = Ap + (size_t)2 * N * EMBD;       // packed emb -> packed x1
    int2*     srec   = (int2*)(xslot + (size_t)N * EMBD);
    int*      cursor = (int*)(srec + E);
    int*      bsum   = cursor + N;

    float* x2 = (float*)Ap;    // gemm-2 fp32 output, aliases Ap[0] rows

    // ---- Pack embedding to split-bf16 ----
    pack_kernel<<<(N * EMBD + 255) / 256, 256, 0, stream>>>(emb, xslot, N * EMBD);

    // ---- Sort edges by dst node (once; shared by both layers) ----
    hipMemsetAsync(cursor, 0, N * sizeof(int), stream);
    hist_kernel<<<(E + 255) / 256, 256, 0, stream>>>(ei, cursor, E);
    scan_local<<<NCHUNK, 256, 0, stream>>>(cursor, bsum, N);
    scan_bsum<<<1, 128, 0, stream>>>(bsum);
    scan_add<<<NCHUNK, 256, 0, stream>>>(cursor, bsum, N);
    bucket_kernel<<<(E + 255) / 256, 256, 0, stream>>>(ei, et, ew, cursor, srec, E);

    // ---- Layer 1: accum (packed emb) -> MFMA GEMM + bias + ReLU + LN ----
    accum_csr<<<N / 4, 256, 0, stream>>>(xslot, srec, cursor, Ap, N);
    gemm_mfma<<<(N + 127) / 128, 256, 0, stream>>>(
        Ap, Ap + (size_t)N * EMBD, xslot,
        w1_rel, w1_root, b1, ln_g, ln_b,
        (void*)xslot /* packed x1, row-aliases packed emb */, N, 1);

    // ---- Layer 2: accum (packed x1) -> MFMA GEMM + bias (fp32 out) ----
    accum_csr<<<N / 4, 256, 0, stream>>>(xslot, srec, cursor, Ap, N);
    gemm_mfma<<<(N + 127) / 128, 256, 0, stream>>>(
        Ap, Ap + (size_t)N * EMBD, xslot,
        w2_rel, w2_root, b2, nullptr, nullptr,
        (void*)x2 /* fp32, row-aliases Ap[0] */, N, 0);

    // ---- Head ----
    head_kernel<<<B / 16, 256, 0, stream>>>(
        x2, ui, vi, mw0, mb0, mw1, mb1, mw2, mb2, ow, ob, out, B);
}